// Round 13
// baseline (47.724 us; speedup 1.0000x reference)
//
#include <hip/hip_runtime.h>

#define BATCH 8
#define NROW  2048
#define NF    64
#define JSPLIT 4
#define JPB   (NROW / JSPLIT)               // 512 k per block (split path)
#define CHUNK 32
#define TOT   ((size_t)BATCH * NROW * NF)   // 1048576

typedef float  f32x4  __attribute__((ext_vector_type(4)));
typedef __bf16 bf16x8 __attribute__((ext_vector_type(8)));
typedef unsigned short u16x8 __attribute__((ext_vector_type(8)));

union frag_cast { u16x8 u; bf16x8 b; };

#define AS1 __attribute__((address_space(1)))
#define AS3 __attribute__((address_space(3)))

__device__ __forceinline__ void gld16u(const unsigned short* g, unsigned short* l) {
  __builtin_amdgcn_global_load_lds((const AS1 void*)g, (AS3 void*)l, 16, 0, 0);
}
__device__ __forceinline__ float ubits(unsigned u) {
  union { unsigned u; float f; } c; c.u = u; return c.f;
}
__device__ __forceinline__ unsigned fbits(float f) {
  union { float f; unsigned u; } c; c.f = f; return c.u;
}

// ---- pass 1: transpose x, split into 3 bf16 levels: xs[lvl][b][f][j] ----
__global__ __launch_bounds__(256, 4)
void prep_x(const float* __restrict__ xg, unsigned short* __restrict__ xs) {
  __shared__ float t[64][65];
  const int b  = blockIdx.y;
  const int j0 = blockIdx.x * 64;
  const int l  = threadIdx.x & 63;
  const int g  = threadIdx.x >> 6;
  const float* src = xg + ((size_t)b * NROW + j0) * NF;
#pragma unroll
  for (int k = 0; k < 16; ++k) {
    const int j = g * 16 + k;
    t[j][l] = src[(size_t)j * NF + l];
  }
  __syncthreads();
#pragma unroll
  for (int k = 0; k < 16; ++k) {
    const int f = g * 16 + k;
    const float v = t[l][f];
    const unsigned u0 = fbits(v);
    const float f0 = ubits(u0 & 0xFFFF0000u);
    const float r  = v - f0;
    const unsigned u1 = fbits(r);
    const float f1 = ubits(u1 & 0xFFFF0000u);
    const float r2 = r - f1;
    const unsigned u2 = fbits(r2);
    const unsigned short s2 =
        (unsigned short)((u2 + 0x7FFFu + ((u2 >> 16) & 1u)) >> 16);
    const size_t o = ((size_t)b * NF + f) * NROW + j0 + l;
    xs[o]           = (unsigned short)(u0 >> 16);
    xs[o + TOT]     = (unsigned short)(u1 >> 16);
    xs[o + 2 * TOT] = s2;
  }
}

// split 8 f32 -> 3 bf16 fragments (proven r5-r12)
__device__ __forceinline__ void split8(const f32x4 q0, const f32x4 q1,
                                       frag_cast* Af) {
  float av[8];
  *(f32x4*)&av[0] = q0;
  *(f32x4*)&av[4] = q1;
  u16x8 h0, h1, h2;
#pragma unroll
  for (int e = 0; e < 8; ++e) {
    const unsigned u0 = fbits(av[e]);
    const float f0 = ubits(u0 & 0xFFFF0000u);
    const float r  = av[e] - f0;
    const unsigned u1 = fbits(r);
    const float f1 = ubits(u1 & 0xFFFF0000u);
    const float r2 = r - f1;
    const unsigned u2 = fbits(r2);
    h0[e] = (unsigned short)(u0 >> 16);
    h1[e] = (unsigned short)(u1 >> 16);
    h2[e] = (unsigned short)((u2 + 0x7FFFu + ((u2 >> 16) & 1u)) >> 16);
  }
  Af[0].u = h0; Af[1].u = h1; Af[2].u = h2;
}

// ---- pass 2: split-bf16 MFMA GEMM, quad-buffered 2-chunk periods ----
// Wave = 16 rows x 64 cols. B: 4 x 12KB LDS bufs via gld_lds (chunk c ->
// buf c&3); A: global->reg, wave-private. Period u (chunks 2u,2u+1):
//   [barrier] stage B(2u+2),B(2u+3) + load A(next period)   (quad => no WAR)
//   compute 2u; compute 2u+1
//   s_waitcnt vmcnt(4)   (own B stages landed; A-loads stay in flight)
//   [barrier]            (=> all waves' stages visible next period)
// B-stages get a full period in flight; barriers halve; A never blocks.
template <bool DIRECT>
__global__ __launch_bounds__(256, 3)
void gemm_mfma(const float* __restrict__ ag, const unsigned short* __restrict__ xs,
               float* __restrict__ outg, float* __restrict__ wp) {
  __shared__ __align__(16) unsigned short sB[4][3 * 64 * CHUNK];   // 4 x 12KB

  const int tid  = threadIdx.x;
  const int ln   = tid & 63;
  const int wv   = tid >> 6;
  const int ln15 = ln & 15;          // A row / B col / D col (in 16-tile)
  const int g    = ln >> 4;          // k-group / D row-group
  const int bkey = (ln15 >> 1) & 3;

  const int flat = blockIdx.x;
  const int b    = flat & 7;                      // batch == XCD
  const int rr   = flat >> 3;
  const int bx   = rr & 31;
  const int z    = DIRECT ? 0 : ((rr >> 5) & 3);
  const int i0   = bx * 64;
  const int jb   = z * JPB;
  const int nch  = (DIRECT ? NROW : JPB) / CHUNK;   // 64 or 16 (even)

  const float* aA =
      ag + ((size_t)b * NROW + i0 + wv * 16 + ln15) * NROW + jb + g * 8;
  const unsigned short* xB = xs + (size_t)b * NF * NROW;

  auto stageB = [&](int buf, int j0) {
#pragma unroll
    for (int lvl = 0; lvl < 3; ++lvl) {
      const int n = tid >> 2;
      const int q = (tid & 3) ^ ((n >> 1) & 3);
      gld16u(xB + (size_t)lvl * TOT + (size_t)n * NROW + j0 + q * 8,
             &sB[buf][0] + (lvl * 256 + wv * 64) * 8);
    }
  };

  double macc[4][4];
#pragma unroll
  for (int i = 0; i < 4; ++i)
#pragma unroll
    for (int j = 0; j < 4; ++j) macc[i][j] = 0.0;

  constexpr int AI[6] = {2, 0, 1, 1, 0, 0};
  constexpr int BI[6] = {0, 2, 1, 0, 1, 0};

  // compute one chunk: B from sB[c&3], A fragments from regs, 24 MFMA, fold
  auto compute = [&](int c, const f32x4 Ar0, const f32x4 Ar1) {
    const unsigned short* sBb = &sB[c & 3][0];
    frag_cast Af[3];
    split8(Ar0, Ar1, Af);
    f32x4 cc[4];
#pragma unroll
    for (int nt = 0; nt < 4; ++nt) cc[nt] = (f32x4){0.f, 0.f, 0.f, 0.f};
#pragma unroll
    for (int ng = 0; ng < 2; ++ng) {
      frag_cast Bv[2][3];
#pragma unroll
      for (int nn = 0; nn < 2; ++nn) {
        const int ncol = (ng * 2 + nn) * 16 + ln15;
        const int bq   = g ^ bkey;
#pragma unroll
        for (int lvl = 0; lvl < 3; ++lvl)
          Bv[nn][lvl].u = *(const u16x8*)(sBb + lvl * 2048 + ncol * 32 + bq * 8);
      }
#pragma unroll
      for (int term = 0; term < 6; ++term)
#pragma unroll
        for (int nn = 0; nn < 2; ++nn) {
          const int nt = ng * 2 + nn;
          cc[nt] = __builtin_amdgcn_mfma_f32_16x16x32_bf16(
              Af[AI[term]].b, Bv[nn][BI[term]].b, cc[nt], 0, 0, 0);
        }
    }
#pragma unroll
    for (int nt = 0; nt < 4; ++nt) {
      macc[nt][0] += (double)cc[nt].x;
      macc[nt][1] += (double)cc[nt].y;
      macc[nt][2] += (double)cc[nt].z;
      macc[nt][3] += (double)cc[nt].w;
    }
  };

  // ---- prologue: chunks 0,1 staged; A(0),A(1) in regs; drain; barrier ----
  stageB(0, jb);
  stageB(1, jb + CHUNK);
  f32x4 Ae0 = *(const f32x4*)(aA);
  f32x4 Ae1 = *(const f32x4*)(aA + 4);
  f32x4 Ao0 = *(const f32x4*)(aA + CHUNK);
  f32x4 Ao1 = *(const f32x4*)(aA + CHUNK + 4);
  asm volatile("s_waitcnt vmcnt(4)" ::: "memory");   // B(0),B(1) landed
  __builtin_amdgcn_s_barrier();
  __builtin_amdgcn_sched_barrier(0);

  const int nper = nch / 2;
#pragma unroll 1
  for (int u = 0; u < nper; ++u) {
    const int c0 = 2 * u, c1 = 2 * u + 1;
    const int s0 = (c0 + 2 < nch) ? c0 + 2 : nch - 1;   // clamped tail
    const int s1 = (c1 + 2 < nch) ? c1 + 2 : nch - 1;

    // stage next period's B into free bufs; issue next period's A loads
    stageB((c0 + 2) & 3, jb + s0 * CHUNK);
    stageB((c1 + 2) & 3, jb + s1 * CHUNK);
    f32x4 An0 = *(const f32x4*)(aA + (size_t)s0 * CHUNK);
    f32x4 An1 = *(const f32x4*)(aA + (size_t)s0 * CHUNK + 4);
    f32x4 Am0 = *(const f32x4*)(aA + (size_t)s1 * CHUNK);
    f32x4 Am1 = *(const f32x4*)(aA + (size_t)s1 * CHUNK + 4);

    compute(c0, Ae0, Ae1);
    compute(c1, Ao0, Ao1);

    Ae0 = An0; Ae1 = An1; Ao0 = Am0; Ao1 = Am1;

    // own B-stages must land before the barrier (cross-wave visibility);
    // the 4 A-loads (newest) stay in flight across it.
    asm volatile("s_waitcnt vmcnt(4)" ::: "memory");
    __builtin_amdgcn_s_barrier();
    __builtin_amdgcn_sched_barrier(0);
  }

  // epilogue: D row = g*4 + r (within 16-tile), col = nt*16 + ln15
  if (DIRECT) {
#pragma unroll
    for (int nt = 0; nt < 4; ++nt)
#pragma unroll
      for (int r = 0; r < 4; ++r)
        outg[((size_t)b * NROW + i0 + wv * 16 + g * 4 + r) * NF + nt * 16 + ln15] =
            (macc[nt][r] > 0.5) ? 1.0f : 0.0f;
  } else {
    float* wb = wp + (size_t)z * TOT;
#pragma unroll
    for (int nt = 0; nt < 4; ++nt)
#pragma unroll
      for (int r = 0; r < 4; ++r)
        wb[((size_t)b * NROW + i0 + wv * 16 + g * 4 + r) * NF + nt * 16 + ln15] =
            (float)macc[nt][r];
  }
}

// ---- pass 3: reduce JSPLIT partials in f64, threshold ----
__global__ __launch_bounds__(256)
void combine_thresh(const float* __restrict__ wsv, float* __restrict__ outg) {
  const size_t e = ((size_t)blockIdx.x * 256 + threadIdx.x) * 4;
  f32x4 p0 = *(const f32x4*)(wsv + e);
  f32x4 p1 = *(const f32x4*)(wsv + e + TOT);
  f32x4 p2 = *(const f32x4*)(wsv + e + 2 * TOT);
  f32x4 p3 = *(const f32x4*)(wsv + e + 3 * TOT);
  f32x4 o;
  o.x = (((double)p0.x + p1.x + p2.x + p3.x) > 0.5) ? 1.0f : 0.0f;
  o.y = (((double)p0.y + p1.y + p2.y + p3.y) > 0.5) ? 1.0f : 0.0f;
  o.z = (((double)p0.z + p1.z + p2.z + p3.z) > 0.5) ? 1.0f : 0.0f;
  o.w = (((double)p0.w + p1.w + p2.w + p3.w) > 0.5) ? 1.0f : 0.0f;
  *(f32x4*)(outg + e) = o;
}

extern "C" void kernel_launch(void* const* d_in, const int* in_sizes, int n_in,
                              void* d_out, int out_size, void* d_ws, size_t ws_size,
                              hipStream_t stream) {
  const float* x = (const float*)d_in[0];
  const float* a = (const float*)d_in[1];
  float* out = (float*)d_out;
  unsigned short* xs = (unsigned short*)d_ws;                 // 6 MB
  float* wp = (float*)((char*)d_ws + 3 * TOT * sizeof(unsigned short));

  prep_x<<<dim3(NROW / 64, BATCH), dim3(256), 0, stream>>>(x, xs);

  const size_t need = 3 * TOT * sizeof(unsigned short)
                    + (size_t)JSPLIT * TOT * sizeof(float);   // 22 MB
  if (ws_size >= need) {
    gemm_mfma<false><<<dim3(JSPLIT * BATCH * (NROW / 64)), dim3(256), 0, stream>>>(
        a, xs, out, wp);
    combine_thresh<<<dim3((unsigned)(TOT / 1024)), dim3(256), 0, stream>>>(wp, out);
  } else {
    gemm_mfma<true><<<dim3(BATCH * (NROW / 64)), dim3(256), 0, stream>>>(
        a, xs, out, nullptr);
  }
}